// Round 1
// baseline (1329.554 us; speedup 1.0000x reference)
//
#include <hip/hip_runtime.h>

#define BLK 256

__global__ void zero_kernel(int* __restrict__ p, int n) {
    int i = blockIdx.x * blockDim.x + threadIdx.x;
    if (i < n) p[i] = 0;
}

__global__ void hist_kernel(const int* __restrict__ dst, int n, int* __restrict__ cnt) {
    int stride = gridDim.x * blockDim.x;
    for (int i = blockIdx.x * blockDim.x + threadIdx.x; i < n; i += stride)
        atomicAdd(&cnt[dst[i]], 1);
}

// Block-wide exclusive scan (256 threads, 16 items/thread/chunk).
__device__ void scan_block(const int* __restrict__ cnt, int* __restrict__ row,
                           int* __restrict__ cur, int n) {
    __shared__ int wsum[4];
    __shared__ int s_carry;
    const int ITEMS = 16;
    const int CHUNK = BLK * ITEMS;
    int lane = threadIdx.x & 63;
    int wv = threadIdx.x >> 6;
    if (threadIdx.x == 0) s_carry = 0;
    __syncthreads();
    for (int base = 0; base < n; base += CHUNK) {
        int idx0 = base + threadIdx.x * ITEMS;
        int v[ITEMS];
        int tsum = 0;
#pragma unroll
        for (int j = 0; j < ITEMS; ++j) {
            int i = idx0 + j;
            v[j] = (i < n) ? cnt[i] : 0;
            tsum += v[j];
        }
        int incl = tsum;
#pragma unroll
        for (int off = 1; off < 64; off <<= 1) {
            int t = __shfl_up(incl, off);
            if (lane >= off) incl += t;
        }
        if (lane == 63) wsum[wv] = incl;
        __syncthreads();
        int carry = s_carry;
        int woff = 0;
        for (int w = 0; w < wv; ++w) woff += wsum[w];
        int excl = carry + woff + (incl - tsum);
#pragma unroll
        for (int j = 0; j < ITEMS; ++j) {
            int i = idx0 + j;
            if (i < n) { row[i] = excl; cur[i] = excl; }
            excl += v[j];
        }
        __syncthreads();
        if (threadIdx.x == 0) s_carry = carry + wsum[0] + wsum[1] + wsum[2] + wsum[3];
        __syncthreads();
    }
    if (threadIdx.x == 0) row[n] = s_carry;
}

__global__ void scan3_kernel(const int* c0, int* r0, int* u0, int n0,
                             const int* c1, int* r1, int* u1, int n1,
                             const int* c2, int* r2, int* u2, int n2) {
    if (blockIdx.x == 0) scan_block(c0, r0, u0, n0);
    else if (blockIdx.x == 1) scan_block(c1, r1, u1, n1);
    else scan_block(c2, r2, u2, n2);
}

__global__ void scatter_kernel(const int* __restrict__ src, const int* __restrict__ dst,
                               int n, int* __restrict__ cur, int* __restrict__ csr) {
    int stride = gridDim.x * blockDim.x;
    for (int i = blockIdx.x * blockDim.x + threadIdx.x; i < n; i += stride) {
        int d = dst[i];
        int pos = atomicAdd(&cur[d], 1);
        csr[pos] = src[i];
    }
}

// One wave per dst node: gather-mean over CSR neighbors (lane = feature),
// then fused dual matvec out = Wl@m + bl + Wr@x_dst with W^T staged in LDS
// as float4-contiguous-per-lane (ds_read_b128, conflict-free).
__launch_bounds__(BLK)
__global__ void sage_layer_kernel(const float* __restrict__ x_src, const float* __restrict__ x_dst,
                                  const int* __restrict__ row_ptr, const int* __restrict__ csr,
                                  const float* __restrict__ Wl, const float* __restrict__ Wr,
                                  const float* __restrict__ bl,
                                  float* __restrict__ out, int n_dst, int do_relu) {
    __shared__ float WlT4[4096];  // [(d>>2)][h][d&3]
    __shared__ float WrT4[4096];
    __shared__ float msh[4][64];
    __shared__ float xsh[4][64];
    int tid = threadIdx.x, lane = tid & 63, wv = tid >> 6;
    for (int i = tid; i < 4096; i += BLK) {
        int h = i >> 6, d = i & 63;
        int j = ((d >> 2) * 64 + h) * 4 + (d & 3);
        WlT4[j] = Wl[i];
        WrT4[j] = Wr[i];
    }
    __syncthreads();
    float bias = bl[lane];
    const float4* Wl4 = (const float4*)WlT4;
    const float4* Wr4 = (const float4*)WrT4;
    const float4* m4 = (const float4*)(msh[wv]);
    const float4* x4 = (const float4*)(xsh[wv]);
    for (int node = blockIdx.x * 4 + wv; node < n_dst; node += gridDim.x * 4) {
        int e0 = row_ptr[node], e1 = row_ptr[node + 1];
        float acc = 0.f;
        for (int e = e0; e < e1; ++e) {
            int s = csr[e];
            acc += x_src[(size_t)s * 64 + lane];
        }
        float m = (e1 > e0) ? acc / (float)(e1 - e0) : 0.f;
        msh[wv][lane] = m;
        xsh[wv][lane] = x_dst[(size_t)node * 64 + lane];
        float o = bias;
#pragma unroll
        for (int dq = 0; dq < 16; ++dq) {
            float4 wl = Wl4[dq * 64 + lane];
            float4 wr = Wr4[dq * 64 + lane];
            float4 mm = m4[dq];
            float4 xx = x4[dq];
            o += wl.x * mm.x + wl.y * mm.y + wl.z * mm.z + wl.w * mm.w;
            o += wr.x * xx.x + wr.y * xx.y + wr.z * xx.z + wr.w * xx.w;
        }
        if (do_relu) o = fmaxf(o, 0.f);
        out[(size_t)node * 64 + lane] = o;
    }
}

extern "C" void kernel_launch(void* const* d_in, const int* in_sizes, int n_in,
                              void* d_out, int out_size, void* d_ws, size_t ws_size,
                              hipStream_t stream) {
    const float* x_user    = (const float*)d_in[0];
    const float* x_problem = (const float*)d_in[1];
    const float* x_topic   = (const float*)d_in[2];
    const int* up_src = (const int*)d_in[3];
    const int* up_dst = (const int*)d_in[4];
    const int* pt_src = (const int*)d_in[5];
    const int* pt_dst = (const int*)d_in[6];
    const int* pu_src = (const int*)d_in[7];
    const int* pu_dst = (const int*)d_in[8];
    const float* W1_up_l = (const float*)d_in[9];
    const float* W1_up_r = (const float*)d_in[10];
    const float* W1_pt_l = (const float*)d_in[11];
    const float* W1_pt_r = (const float*)d_in[12];
    const float* W1_pu_l = (const float*)d_in[13];
    const float* W1_pu_r = (const float*)d_in[14];
    const float* W2_up_l = (const float*)d_in[15];
    const float* W2_up_r = (const float*)d_in[16];
    const float* W2_pt_l = (const float*)d_in[17];
    const float* W2_pt_r = (const float*)d_in[18];
    const float* W2_pu_l = (const float*)d_in[19];
    const float* W2_pu_r = (const float*)d_in[20];
    const float* b1_up = (const float*)d_in[21];
    const float* b1_pt = (const float*)d_in[22];
    const float* b1_pu = (const float*)d_in[23];
    const float* b2_up = (const float*)d_in[24];
    const float* b2_pt = (const float*)d_in[25];
    const float* b2_pu = (const float*)d_in[26];

    int n_user = in_sizes[0] / 64;
    int n_problem = in_sizes[1] / 64;
    int n_topic = in_sizes[2] / 64;
    int E_up = in_sizes[3];
    int E_pt = in_sizes[5];
    int E_pu = in_sizes[7];

    float* o_user = (float*)d_out;
    float* o_problem = o_user + (size_t)n_user * 64;
    float* o_topic = o_problem + (size_t)n_problem * 64;

    char* ws = (char*)d_ws;
    size_t off = 0;
    auto alloc = [&](size_t bytes) -> void* {
        void* p = ws + off;
        off += (bytes + 255) & ~(size_t)255;
        return p;
    };
    float* h_user    = (float*)alloc((size_t)n_user * 64 * 4);
    float* h_problem = (float*)alloc((size_t)n_problem * 64 * 4);
    float* h_topic   = (float*)alloc((size_t)n_topic * 64 * 4);
    int ncnt = n_problem + n_topic + n_user;
    int* cnt_up = (int*)alloc((size_t)ncnt * 4);
    int* cnt_pt = cnt_up + n_problem;
    int* cnt_pu = cnt_pt + n_topic;
    int* row_up = (int*)alloc(((size_t)n_problem + 1) * 4);
    int* row_pt = (int*)alloc(((size_t)n_topic + 1) * 4);
    int* row_pu = (int*)alloc(((size_t)n_user + 1) * 4);
    int* cur_up = (int*)alloc((size_t)n_problem * 4);
    int* cur_pt = (int*)alloc((size_t)n_topic * 4);
    int* cur_pu = (int*)alloc((size_t)n_user * 4);
    int* csr_up = (int*)alloc((size_t)E_up * 4);
    int* csr_pt = (int*)alloc((size_t)E_pt * 4);
    int* csr_pu = (int*)alloc((size_t)E_pu * 4);

    auto grid_for = [](int n, int per_blk, int cap) {
        int g = (n + per_blk - 1) / per_blk;
        return g < cap ? (g > 0 ? g : 1) : cap;
    };

    zero_kernel<<<grid_for(ncnt, 256, 1 << 20), 256, 0, stream>>>(cnt_up, ncnt);
    hist_kernel<<<grid_for(E_up, 256, 4096), 256, 0, stream>>>(up_dst, E_up, cnt_up);
    hist_kernel<<<grid_for(E_pt, 256, 4096), 256, 0, stream>>>(pt_dst, E_pt, cnt_pt);
    hist_kernel<<<grid_for(E_pu, 256, 4096), 256, 0, stream>>>(pu_dst, E_pu, cnt_pu);
    scan3_kernel<<<3, BLK, 0, stream>>>(cnt_up, row_up, cur_up, n_problem,
                                        cnt_pt, row_pt, cur_pt, n_topic,
                                        cnt_pu, row_pu, cur_pu, n_user);
    scatter_kernel<<<grid_for(E_up, 256, 4096), 256, 0, stream>>>(up_src, up_dst, E_up, cur_up, csr_up);
    scatter_kernel<<<grid_for(E_pt, 256, 4096), 256, 0, stream>>>(pt_src, pt_dst, E_pt, cur_pt, csr_pt);
    scatter_kernel<<<grid_for(E_pu, 256, 4096), 256, 0, stream>>>(pu_src, pu_dst, E_pu, cur_pu, csr_pu);

    auto L = [&](const float* xs, const float* xd, const int* row, const int* csr,
                 const float* Wl, const float* Wr, const float* bb, float* o, int nd, int relu) {
        int grid = (nd + 3) / 4;
        if (grid > 32768) grid = 32768;
        sage_layer_kernel<<<grid, BLK, 0, stream>>>(xs, xd, row, csr, Wl, Wr, bb, o, nd, relu);
    };
    // layer 1 (ReLU)
    L(x_user,    x_problem, row_up, csr_up, W1_up_l, W1_up_r, b1_up, h_problem, n_problem, 1);
    L(x_problem, x_topic,   row_pt, csr_pt, W1_pt_l, W1_pt_r, b1_pt, h_topic,   n_topic,   1);
    L(x_problem, x_user,    row_pu, csr_pu, W1_pu_l, W1_pu_r, b1_pu, h_user,    n_user,    1);
    // layer 2 (no ReLU)
    L(h_user,    h_problem, row_up, csr_up, W2_up_l, W2_up_r, b2_up, o_problem, n_problem, 0);
    L(h_problem, h_topic,   row_pt, csr_pt, W2_pt_l, W2_pt_r, b2_pt, o_topic,   n_topic,   0);
    L(h_problem, h_user,    row_pu, csr_pu, W2_pu_l, W2_pu_r, b2_pu, o_user,    n_user,    0);
}

// Round 3
// 628.187 us; speedup vs baseline: 2.1165x; 2.1165x over previous
//
#include <hip/hip_runtime.h>

#define BLK 256

// ---------------- CSR build ----------------

__global__ void zero_kernel(int* __restrict__ p, int n) {
    int i = blockIdx.x * blockDim.x + threadIdx.x;
    if (i < n) p[i] = 0;
}

struct EJobs {
    const int* src[3];
    const int* dst[3];
    int* cnt[3];   // hist: counter; scatter: cursor
    int* csr[3];
    int E[3];
    int boff[4];
};

__launch_bounds__(BLK)
__global__ void hist_kernel(EJobs J) {
    int b = blockIdx.x, j = 0;
    while (b >= J.boff[j + 1]) ++j;
    int i = (b - J.boff[j]) * BLK + threadIdx.x;
    if (i < J.E[j]) atomicAdd(&J.cnt[j][J.dst[j][i]], 1);
}

__launch_bounds__(BLK)
__global__ void scatter_kernel(EJobs J) {
    int b = blockIdx.x, j = 0;
    while (b >= J.boff[j + 1]) ++j;
    int i = (b - J.boff[j]) * BLK + threadIdx.x;
    if (i < J.E[j]) {
        int d = J.dst[j][i];
        int pos = atomicAdd(&J.cnt[j][d], 1);
        J.csr[j][pos] = J.src[j][i];
    }
}

// Block-wide exclusive scan (256 threads, 16 items/thread/chunk).
__device__ void scan_block(const int* __restrict__ cnt, int* __restrict__ row,
                           int* __restrict__ cur, int n) {
    __shared__ int wsum[4];
    __shared__ int s_carry;
    const int ITEMS = 16;
    const int CHUNK = BLK * ITEMS;
    int lane = threadIdx.x & 63;
    int wv = threadIdx.x >> 6;
    if (threadIdx.x == 0) s_carry = 0;
    __syncthreads();
    for (int base = 0; base < n; base += CHUNK) {
        int idx0 = base + threadIdx.x * ITEMS;
        int v[ITEMS];
        int tsum = 0;
#pragma unroll
        for (int j = 0; j < ITEMS; ++j) {
            int i = idx0 + j;
            v[j] = (i < n) ? cnt[i] : 0;
            tsum += v[j];
        }
        int incl = tsum;
#pragma unroll
        for (int off = 1; off < 64; off <<= 1) {
            int t = __shfl_up(incl, off);
            if (lane >= off) incl += t;
        }
        if (lane == 63) wsum[wv] = incl;
        __syncthreads();
        int carry = s_carry;
        int woff = 0;
        for (int w = 0; w < wv; ++w) woff += wsum[w];
        int excl = carry + woff + (incl - tsum);
#pragma unroll
        for (int j = 0; j < ITEMS; ++j) {
            int i = idx0 + j;
            if (i < n) { row[i] = excl; cur[i] = excl; }
            excl += v[j];
        }
        __syncthreads();
        if (threadIdx.x == 0) s_carry = carry + wsum[0] + wsum[1] + wsum[2] + wsum[3];
        __syncthreads();
    }
    if (threadIdx.x == 0) row[n] = s_carry;
}

__global__ void scan3_kernel(const int* c0, int* r0, int* u0, int n0,
                             const int* c1, int* r1, int* u1, int n1,
                             const int* c2, int* r2, int* u2, int n2) {
    if (blockIdx.x == 0) scan_block(c0, r0, u0, n0);
    else if (blockIdx.x == 1) scan_block(c1, r1, u1, n1);
    else scan_block(c2, r2, u2, n2);
}

// ---------------- Dense transform: y = x @ W^T (+ b) ----------------
// Register-tiled: block computes 64 nodes x 64 outputs; thread = 4 nodes x 4 h.

struct TJobs {
    const float* x[6];
    const float* W[6];
    const float* b[6];   // null -> no bias
    float* y[6];
    int n[6];
    int boff[7];
};

__device__ inline void fma4(float4& a, float s, const float4& w) {
    a.x = fmaf(s, w.x, a.x);
    a.y = fmaf(s, w.y, a.y);
    a.z = fmaf(s, w.z, a.z);
    a.w = fmaf(s, w.w, a.w);
}

#define TPAD 68

__launch_bounds__(BLK)
__global__ void transform_kernel(TJobs J) {
    __shared__ float xT[64][TPAD];
    __shared__ float wT[64][TPAD];
    int b = blockIdx.x, j = 0;
    while (b >= J.boff[j + 1]) ++j;
    int tile = b - J.boff[j];
    int n = J.n[j];
    int n0 = tile * 64;
    const float* __restrict__ x = J.x[j];
    const float* __restrict__ W = J.W[j];
    const float* bb = J.b[j];
    float* __restrict__ y = J.y[j];

    int tid = threadIdx.x;
    int tx = tid & 15, ty = tid >> 4;  // tx: h-quad, ty: 0..15
#pragma unroll
    for (int r = 0; r < 4; ++r) {
        int h = r * 16 + ty, d = tx * 4;
        float4 w4 = *(const float4*)&W[h * 64 + d];
        wT[d + 0][h] = w4.x; wT[d + 1][h] = w4.y; wT[d + 2][h] = w4.z; wT[d + 3][h] = w4.w;
        int nn = r * 16 + ty;
        float4 v = make_float4(0.f, 0.f, 0.f, 0.f);
        if (n0 + nn < n) v = *(const float4*)&x[(size_t)(n0 + nn) * 64 + d];
        xT[d + 0][nn] = v.x; xT[d + 1][nn] = v.y; xT[d + 2][nn] = v.z; xT[d + 3][nn] = v.w;
    }
    __syncthreads();

    float4 bias = make_float4(0.f, 0.f, 0.f, 0.f);
    if (bb) bias = *(const float4*)&bb[tx * 4];
    float4 acc0 = bias, acc1 = bias, acc2 = bias, acc3 = bias;
#pragma unroll
    for (int k = 0; k < 64; ++k) {
        float4 a = *(const float4*)&xT[k][ty * 4];
        float4 w = *(const float4*)&wT[k][tx * 4];
        fma4(acc0, a.x, w);
        fma4(acc1, a.y, w);
        fma4(acc2, a.z, w);
        fma4(acc3, a.w, w);
    }
    int nb = n0 + ty * 4;
    if (nb + 0 < n) *(float4*)&y[(size_t)(nb + 0) * 64 + tx * 4] = acc0;
    if (nb + 1 < n) *(float4*)&y[(size_t)(nb + 1) * 64 + tx * 4] = acc1;
    if (nb + 2 < n) *(float4*)&y[(size_t)(nb + 2) * 64 + tx * 4] = acc2;
    if (nb + 3 < n) *(float4*)&y[(size_t)(nb + 3) * 64 + tx * 4] = acc3;
}

// ---------------- Gather-mean + add (RMW into out) ----------------
// One wave per dst node, lane = feature, 4-way unrolled edge loop, no LDS.

struct GJobs {
    const float* y[3];
    const int* row[3];
    const int* csr[3];
    float* out[3];
    int n[3];
    int boff[4];
    int relu;
};

__launch_bounds__(BLK)
__global__ void gather_kernel(GJobs J) {
    int b = blockIdx.x, j = 0;
    while (b >= J.boff[j + 1]) ++j;
    int lane = threadIdx.x & 63, wv = threadIdx.x >> 6;
    int node = (b - J.boff[j]) * 4 + wv;
    if (node >= J.n[j]) return;
    const int* __restrict__ row = J.row[j];
    const int* __restrict__ csr = J.csr[j];
    const float* __restrict__ y = J.y[j];
    float* __restrict__ out = J.out[j];

    int e0 = row[node], e1 = row[node + 1];
    float a0 = 0.f, a1 = 0.f, a2 = 0.f, a3 = 0.f;
    int e = e0;
    for (; e + 4 <= e1; e += 4) {
        int s0 = csr[e + 0];
        int s1 = csr[e + 1];
        int s2 = csr[e + 2];
        int s3 = csr[e + 3];
        a0 += y[(size_t)s0 * 64 + lane];
        a1 += y[(size_t)s1 * 64 + lane];
        a2 += y[(size_t)s2 * 64 + lane];
        a3 += y[(size_t)s3 * 64 + lane];
    }
    for (; e < e1; ++e) a0 += y[(size_t)csr[e] * 64 + lane];
    int deg = e1 - e0;
    float m = (a0 + a1) + (a2 + a3);
    m = deg ? m / (float)deg : 0.f;
    size_t oi = (size_t)node * 64 + lane;
    float o = m + out[oi];
    if (J.relu) o = fmaxf(o, 0.f);
    out[oi] = o;
}

// ---------------- Host ----------------

extern "C" void kernel_launch(void* const* d_in, const int* in_sizes, int n_in,
                              void* d_out, int out_size, void* d_ws, size_t ws_size,
                              hipStream_t stream) {
    const float* x_user    = (const float*)d_in[0];
    const float* x_problem = (const float*)d_in[1];
    const float* x_topic   = (const float*)d_in[2];
    const int* up_src = (const int*)d_in[3];
    const int* up_dst = (const int*)d_in[4];
    const int* pt_src = (const int*)d_in[5];
    const int* pt_dst = (const int*)d_in[6];
    const int* pu_src = (const int*)d_in[7];
    const int* pu_dst = (const int*)d_in[8];
    const float* W1_up_l = (const float*)d_in[9];
    const float* W1_up_r = (const float*)d_in[10];
    const float* W1_pt_l = (const float*)d_in[11];
    const float* W1_pt_r = (const float*)d_in[12];
    const float* W1_pu_l = (const float*)d_in[13];
    const float* W1_pu_r = (const float*)d_in[14];
    const float* W2_up_l = (const float*)d_in[15];
    const float* W2_up_r = (const float*)d_in[16];
    const float* W2_pt_l = (const float*)d_in[17];
    const float* W2_pt_r = (const float*)d_in[18];
    const float* W2_pu_l = (const float*)d_in[19];
    const float* W2_pu_r = (const float*)d_in[20];
    const float* b1_up = (const float*)d_in[21];
    const float* b1_pt = (const float*)d_in[22];
    const float* b1_pu = (const float*)d_in[23];
    const float* b2_up = (const float*)d_in[24];
    const float* b2_pt = (const float*)d_in[25];
    const float* b2_pu = (const float*)d_in[26];

    int n_user = in_sizes[0] / 64;
    int n_problem = in_sizes[1] / 64;
    int n_topic = in_sizes[2] / 64;
    int E_up = in_sizes[3];
    int E_pt = in_sizes[5];
    int E_pu = in_sizes[7];

    float* o_user = (float*)d_out;
    float* o_problem = o_user + (size_t)n_user * 64;
    float* o_topic = o_problem + (size_t)n_problem * 64;

    char* ws = (char*)d_ws;
    size_t off = 0;
    auto alloc = [&](size_t bytes) -> void* {
        void* p = ws + off;
        off += (bytes + 255) & ~(size_t)255;
        return p;
    };
    float* h_user    = (float*)alloc((size_t)n_user * 64 * 4);
    float* h_problem = (float*)alloc((size_t)n_problem * 64 * 4);
    float* h_topic   = (float*)alloc((size_t)n_topic * 64 * 4);
    float* y_up = (float*)alloc((size_t)n_user * 64 * 4);      // transform of up-src
    float* y_pt = (float*)alloc((size_t)n_problem * 64 * 4);
    float* y_pu = (float*)alloc((size_t)n_problem * 64 * 4);
    int ncnt = n_problem + n_topic + n_user;
    int* cnt_up = (int*)alloc((size_t)ncnt * 4);
    int* cnt_pt = cnt_up + n_problem;
    int* cnt_pu = cnt_pt + n_topic;
    int* row_up = (int*)alloc(((size_t)n_problem + 1) * 4);
    int* row_pt = (int*)alloc(((size_t)n_topic + 1) * 4);
    int* row_pu = (int*)alloc(((size_t)n_user + 1) * 4);
    int* cur_up = (int*)alloc((size_t)n_problem * 4);
    int* cur_pt = (int*)alloc((size_t)n_topic * 4);
    int* cur_pu = (int*)alloc((size_t)n_user * 4);
    int* csr_up = (int*)alloc((size_t)E_up * 4);
    int* csr_pt = (int*)alloc((size_t)E_pt * 4);
    int* csr_pu = (int*)alloc((size_t)E_pu * 4);

    auto cdiv = [](int a, int b) { return (a + b - 1) / b; };

    // CSR build
    zero_kernel<<<cdiv(ncnt, 256), 256, 0, stream>>>(cnt_up, ncnt);

    EJobs EH;
    EH.src[0] = up_src; EH.dst[0] = up_dst; EH.cnt[0] = cnt_up; EH.csr[0] = csr_up; EH.E[0] = E_up;
    EH.src[1] = pt_src; EH.dst[1] = pt_dst; EH.cnt[1] = cnt_pt; EH.csr[1] = csr_pt; EH.E[1] = E_pt;
    EH.src[2] = pu_src; EH.dst[2] = pu_dst; EH.cnt[2] = cnt_pu; EH.csr[2] = csr_pu; EH.E[2] = E_pu;
    EH.boff[0] = 0;
    for (int j = 0; j < 3; ++j) EH.boff[j + 1] = EH.boff[j] + cdiv(EH.E[j], BLK);
    hist_kernel<<<EH.boff[3], BLK, 0, stream>>>(EH);

    scan3_kernel<<<3, BLK, 0, stream>>>(cnt_up, row_up, cur_up, n_problem,
                                        cnt_pt, row_pt, cur_pt, n_topic,
                                        cnt_pu, row_pu, cur_pu, n_user);

    EJobs ES = EH;
    ES.cnt[0] = cur_up; ES.cnt[1] = cur_pt; ES.cnt[2] = cur_pu;
    scatter_kernel<<<ES.boff[3], BLK, 0, stream>>>(ES);

    // ---- layer 1 ----
    {
        TJobs T;
        const float* xs[6] = {x_user, x_problem, x_problem, x_problem, x_topic, x_user};
        const float* Ws[6] = {W1_up_l, W1_pt_l, W1_pu_l, W1_up_r, W1_pt_r, W1_pu_r};
        const float* bs[6] = {nullptr, nullptr, nullptr, b1_up, b1_pt, b1_pu};
        float* ys[6] = {y_up, y_pt, y_pu, h_problem, h_topic, h_user};
        int ns[6] = {n_user, n_problem, n_problem, n_problem, n_topic, n_user};
        T.boff[0] = 0;
        for (int j = 0; j < 6; ++j) {
            T.x[j] = xs[j]; T.W[j] = Ws[j]; T.b[j] = bs[j]; T.y[j] = ys[j]; T.n[j] = ns[j];
            T.boff[j + 1] = T.boff[j] + cdiv(ns[j], 64);
        }
        transform_kernel<<<T.boff[6], BLK, 0, stream>>>(T);

        GJobs G;
        const float* gy[3] = {y_pu, y_up, y_pt};
        const int* gr[3] = {row_pu, row_up, row_pt};
        const int* gc[3] = {csr_pu, csr_up, csr_pt};
        float* go[3] = {h_user, h_problem, h_topic};
        int gn[3] = {n_user, n_problem, n_topic};
        G.boff[0] = 0;
        for (int j = 0; j < 3; ++j) {
            G.y[j] = gy[j]; G.row[j] = gr[j]; G.csr[j] = gc[j]; G.out[j] = go[j]; G.n[j] = gn[j];
            G.boff[j + 1] = G.boff[j] + cdiv(gn[j], 4);
        }
        G.relu = 1;
        gather_kernel<<<G.boff[3], BLK, 0, stream>>>(G);
    }

    // ---- layer 2 ----
    {
        TJobs T;
        // self-term sources: o_problem<-h_problem, o_topic<-h_topic, o_user<-h_user
        const float* xs[6] = {h_user, h_problem, h_problem, h_problem, h_topic, h_user};
        const float* Ws[6] = {W2_up_l, W2_pt_l, W2_pu_l, W2_up_r, W2_pt_r, W2_pu_r};
        const float* bs[6] = {nullptr, nullptr, nullptr, b2_up, b2_pt, b2_pu};
        float* ys[6] = {y_up, y_pt, y_pu, o_problem, o_topic, o_user};
        int ns[6] = {n_user, n_problem, n_problem, n_problem, n_topic, n_user};
        T.boff[0] = 0;
        for (int j = 0; j < 6; ++j) {
            T.x[j] = xs[j]; T.W[j] = Ws[j]; T.b[j] = bs[j]; T.y[j] = ys[j]; T.n[j] = ns[j];
            T.boff[j + 1] = T.boff[j] + cdiv(ns[j], 64);
        }
        transform_kernel<<<T.boff[6], BLK, 0, stream>>>(T);

        GJobs G;
        const float* gy[3] = {y_pu, y_up, y_pt};
        const int* gr[3] = {row_pu, row_up, row_pt};
        const int* gc[3] = {csr_pu, csr_up, csr_pt};
        float* go[3] = {o_user, o_problem, o_topic};
        int gn[3] = {n_user, n_problem, n_topic};
        G.boff[0] = 0;
        for (int j = 0; j < 3; ++j) {
            G.y[j] = gy[j]; G.row[j] = gr[j]; G.csr[j] = gc[j]; G.out[j] = go[j]; G.n[j] = gn[j];
            G.boff[j + 1] = G.boff[j] + cdiv(gn[j], 4);
        }
        G.relu = 0;
        gather_kernel<<<G.boff[3], BLK, 0, stream>>>(G);
    }
}

// Round 4
// 363.619 us; speedup vs baseline: 3.6564x; 1.7276x over previous
//
#include <hip/hip_runtime.h>

#define BLK 256
#define SB_SHIFT 7          // 128 dst per bucket
#define NBMAX 576
#define CHUNK_E 4096

// ---------------- generic zero ----------------

__global__ void zero_kernel(int* __restrict__ p, int n) {
    int i = blockIdx.x * blockDim.x + threadIdx.x;
    if (i < n) p[i] = 0;
}

// ---------------- bucketed CSR build ----------------

struct BJobs {
    const int* src[3];
    const int* dst[3];
    int E[3];
    int Eoff[4];       // concat edge offsets per relation
    int nboff[4];      // concat bucket-id offsets per relation
    int ndst[3];
    int Roff[3];       // row_ptr concat offsets per relation
    int chunk_off[4];  // chunk-block offsets per relation
};

__launch_bounds__(BLK)
__global__ void bhist_kernel(BJobs J, int* __restrict__ gcnt, int NB) {
    __shared__ int lc[NBMAX];
    int tid = threadIdx.x;
    for (int i = tid; i < NB; i += BLK) lc[i] = 0;
    __syncthreads();
    int b = blockIdx.x, r = 0;
    while (b >= J.chunk_off[r + 1]) ++r;
    int e0 = (b - J.chunk_off[r]) * CHUNK_E;
    int e1 = min(e0 + CHUNK_E, J.E[r]);
    const int* __restrict__ dst = J.dst[r];
    int base = J.nboff[r];
    for (int e = e0 + tid; e < e1; e += BLK)
        atomicAdd(&lc[base + (dst[e] >> SB_SHIFT)], 1);
    __syncthreads();
    for (int i = tid; i < NB; i += BLK)
        if (lc[i]) atomicAdd(&gcnt[i], lc[i]);
}

// Block-wide exclusive scan (256 threads, 16 items/thread/chunk).
__device__ void scan_block(const int* __restrict__ cnt, int* __restrict__ row,
                           int* __restrict__ cur, int n) {
    __shared__ int wsum[4];
    __shared__ int s_carry;
    const int ITEMS = 16;
    const int CHUNK = BLK * ITEMS;
    int lane = threadIdx.x & 63;
    int wv = threadIdx.x >> 6;
    if (threadIdx.x == 0) s_carry = 0;
    __syncthreads();
    for (int base = 0; base < n; base += CHUNK) {
        int idx0 = base + threadIdx.x * ITEMS;
        int v[ITEMS];
        int tsum = 0;
#pragma unroll
        for (int j = 0; j < ITEMS; ++j) {
            int i = idx0 + j;
            v[j] = (i < n) ? cnt[i] : 0;
            tsum += v[j];
        }
        int incl = tsum;
#pragma unroll
        for (int off = 1; off < 64; off <<= 1) {
            int t = __shfl_up(incl, off);
            if (lane >= off) incl += t;
        }
        if (lane == 63) wsum[wv] = incl;
        __syncthreads();
        int carry = s_carry;
        int woff = 0;
        for (int w = 0; w < wv; ++w) woff += wsum[w];
        int excl = carry + woff + (incl - tsum);
#pragma unroll
        for (int j = 0; j < ITEMS; ++j) {
            int i = idx0 + j;
            if (i < n) { row[i] = excl; cur[i] = excl; }
            excl += v[j];
        }
        __syncthreads();
        if (threadIdx.x == 0) s_carry = carry + wsum[0] + wsum[1] + wsum[2] + wsum[3];
        __syncthreads();
    }
    if (threadIdx.x == 0) row[n] = s_carry;
}

__global__ void bscan_kernel(const int* __restrict__ gcnt, int* __restrict__ bbase,
                             int* __restrict__ bcur, int n) {
    scan_block(gcnt, bbase, bcur, n);
}

__launch_bounds__(BLK)
__global__ void bbin_kernel(BJobs J, int* __restrict__ bcur, int2* __restrict__ ebuf, int NB) {
    __shared__ int lc[NBMAX];
    __shared__ int res[NBMAX];
    __shared__ int cur[NBMAX];
    int tid = threadIdx.x;
    for (int i = tid; i < NB; i += BLK) { lc[i] = 0; cur[i] = 0; }
    __syncthreads();
    int b = blockIdx.x, r = 0;
    while (b >= J.chunk_off[r + 1]) ++r;
    int e0 = (b - J.chunk_off[r]) * CHUNK_E;
    int e1 = min(e0 + CHUNK_E, J.E[r]);
    const int* __restrict__ src = J.src[r];
    const int* __restrict__ dst = J.dst[r];
    int base = J.nboff[r];
    for (int e = e0 + tid; e < e1; e += BLK)
        atomicAdd(&lc[base + (dst[e] >> SB_SHIFT)], 1);
    __syncthreads();
    for (int i = tid; i < NB; i += BLK)
        if (lc[i]) res[i] = atomicAdd(&bcur[i], lc[i]);
    __syncthreads();
    for (int e = e0 + tid; e < e1; e += BLK) {
        int s = src[e], d = dst[e];
        int bk = base + (d >> SB_SHIFT);
        int l = atomicAdd(&cur[bk], 1);
        ebuf[res[bk] + l] = make_int2(s, d);
    }
}

// One block per bucket: per-dst count, 128-wide scan, write row_ptr, place edges.
__launch_bounds__(BLK)
__global__ void bplace_kernel(BJobs J, const int* __restrict__ bbase,
                              const int2* __restrict__ ebuf,
                              int* __restrict__ ccsr, int* __restrict__ rowcat) {
    __shared__ int cnt[128];
    __shared__ int off[128];
    __shared__ int cur[128];
    int tid = threadIdx.x;
    int bk = blockIdx.x, r = 0;
    while (bk >= J.nboff[r + 1]) ++r;
    int dst0 = (bk - J.nboff[r]) << SB_SHIFT;
    int nd = J.ndst[r] - dst0;
    if (nd > 128) nd = 128;
    int ebase = bbase[bk], eend = bbase[bk + 1];
    if (tid < 128) cnt[tid] = 0;
    __syncthreads();
    for (int e = ebase + tid; e < eend; e += BLK)
        atomicAdd(&cnt[ebuf[e].y - dst0], 1);
    __syncthreads();
    if (tid < 128) off[tid] = cnt[tid];
    __syncthreads();
    for (int st = 1; st < 128; st <<= 1) {
        int v = 0;
        if (tid < 128 && tid >= st) v = off[tid - st];
        __syncthreads();
        if (tid < 128) off[tid] += v;
        __syncthreads();
    }
    int Eo = J.Eoff[r];
    int* __restrict__ row = rowcat + J.Roff[r];
    if (tid < nd) {
        int ex = off[tid] - cnt[tid];           // exclusive within-bucket offset
        row[dst0 + tid] = ebase + ex - Eo;      // relation-relative
        cur[tid] = ex;
    }
    if (tid == 0 && dst0 + nd == J.ndst[r])
        row[J.ndst[r]] = bbase[J.nboff[r + 1]] - Eo;
    __syncthreads();
    for (int e = ebase + tid; e < eend; e += BLK) {
        int2 sd = ebuf[e];
        int l = atomicAdd(&cur[sd.y - dst0], 1);
        ccsr[ebase + l] = sd.x;
    }
}

// ---------------- Dense transform: y = x @ W^T (+ b) ----------------

struct TJobs {
    const float* x[6];
    const float* W[6];
    const float* b[6];
    float* y[6];
    int n[6];
    int boff[7];
};

__device__ inline void fma4(float4& a, float s, const float4& w) {
    a.x = fmaf(s, w.x, a.x);
    a.y = fmaf(s, w.y, a.y);
    a.z = fmaf(s, w.z, a.z);
    a.w = fmaf(s, w.w, a.w);
}

#define TPAD 68

__launch_bounds__(BLK)
__global__ void transform_kernel(TJobs J) {
    __shared__ float xT[64][TPAD];
    __shared__ float wT[64][TPAD];
    int b = blockIdx.x, j = 0;
    while (b >= J.boff[j + 1]) ++j;
    int tile = b - J.boff[j];
    int n = J.n[j];
    int n0 = tile * 64;
    const float* __restrict__ x = J.x[j];
    const float* __restrict__ W = J.W[j];
    const float* bb = J.b[j];
    float* __restrict__ y = J.y[j];

    int tid = threadIdx.x;
    int tx = tid & 15, ty = tid >> 4;
#pragma unroll
    for (int r = 0; r < 4; ++r) {
        int h = r * 16 + ty, d = tx * 4;
        float4 w4 = *(const float4*)&W[h * 64 + d];
        wT[d + 0][h] = w4.x; wT[d + 1][h] = w4.y; wT[d + 2][h] = w4.z; wT[d + 3][h] = w4.w;
        int nn = r * 16 + ty;
        float4 v = make_float4(0.f, 0.f, 0.f, 0.f);
        if (n0 + nn < n) v = *(const float4*)&x[(size_t)(n0 + nn) * 64 + d];
        xT[d + 0][nn] = v.x; xT[d + 1][nn] = v.y; xT[d + 2][nn] = v.z; xT[d + 3][nn] = v.w;
    }
    __syncthreads();

    float4 bias = make_float4(0.f, 0.f, 0.f, 0.f);
    if (bb) bias = *(const float4*)&bb[tx * 4];
    float4 acc0 = bias, acc1 = bias, acc2 = bias, acc3 = bias;
#pragma unroll
    for (int k = 0; k < 64; ++k) {
        float4 a = *(const float4*)&xT[k][ty * 4];
        float4 w = *(const float4*)&wT[k][tx * 4];
        fma4(acc0, a.x, w);
        fma4(acc1, a.y, w);
        fma4(acc2, a.z, w);
        fma4(acc3, a.w, w);
    }
    int nb = n0 + ty * 4;
    if (nb + 0 < n) *(float4*)&y[(size_t)(nb + 0) * 64 + tx * 4] = acc0;
    if (nb + 1 < n) *(float4*)&y[(size_t)(nb + 1) * 64 + tx * 4] = acc1;
    if (nb + 2 < n) *(float4*)&y[(size_t)(nb + 2) * 64 + tx * 4] = acc2;
    if (nb + 3 < n) *(float4*)&y[(size_t)(nb + 3) * 64 + tx * 4] = acc3;
}

// ---------------- Gather-mean + add (RMW into out), 8-way unrolled ----------------

struct GJobs {
    const float* y[3];
    const int* row[3];
    const int* csr[3];
    float* out[3];
    int n[3];
    int boff[4];
    int relu;
};

__launch_bounds__(BLK)
__global__ void gather_kernel(GJobs J) {
    int b = blockIdx.x, j = 0;
    while (b >= J.boff[j + 1]) ++j;
    int lane = threadIdx.x & 63, wv = threadIdx.x >> 6;
    int node = (b - J.boff[j]) * 4 + wv;
    if (node >= J.n[j]) return;
    const int* __restrict__ row = J.row[j];
    const int* __restrict__ csr = J.csr[j];
    const float* __restrict__ y = J.y[j];
    float* __restrict__ out = J.out[j];

    int e0 = row[node], e1 = row[node + 1];
    float a0 = 0.f, a1 = 0.f, a2 = 0.f, a3 = 0.f;
    float a4 = 0.f, a5 = 0.f, a6 = 0.f, a7 = 0.f;
    int e = e0;
    for (; e + 8 <= e1; e += 8) {
        int s0 = csr[e + 0], s1 = csr[e + 1], s2 = csr[e + 2], s3 = csr[e + 3];
        int s4 = csr[e + 4], s5 = csr[e + 5], s6 = csr[e + 6], s7 = csr[e + 7];
        a0 += y[(size_t)s0 * 64 + lane];
        a1 += y[(size_t)s1 * 64 + lane];
        a2 += y[(size_t)s2 * 64 + lane];
        a3 += y[(size_t)s3 * 64 + lane];
        a4 += y[(size_t)s4 * 64 + lane];
        a5 += y[(size_t)s5 * 64 + lane];
        a6 += y[(size_t)s6 * 64 + lane];
        a7 += y[(size_t)s7 * 64 + lane];
    }
    for (; e < e1; ++e) a0 += y[(size_t)csr[e] * 64 + lane];
    int deg = e1 - e0;
    float m = ((a0 + a1) + (a2 + a3)) + ((a4 + a5) + (a6 + a7));
    m = deg ? m / (float)deg : 0.f;
    size_t oi = (size_t)node * 64 + lane;
    float o = m + out[oi];
    if (J.relu) o = fmaxf(o, 0.f);
    out[oi] = o;
}

// ---------------- Host ----------------

extern "C" void kernel_launch(void* const* d_in, const int* in_sizes, int n_in,
                              void* d_out, int out_size, void* d_ws, size_t ws_size,
                              hipStream_t stream) {
    const float* x_user    = (const float*)d_in[0];
    const float* x_problem = (const float*)d_in[1];
    const float* x_topic   = (const float*)d_in[2];
    const int* up_src = (const int*)d_in[3];
    const int* up_dst = (const int*)d_in[4];
    const int* pt_src = (const int*)d_in[5];
    const int* pt_dst = (const int*)d_in[6];
    const int* pu_src = (const int*)d_in[7];
    const int* pu_dst = (const int*)d_in[8];
    const float* W1_up_l = (const float*)d_in[9];
    const float* W1_up_r = (const float*)d_in[10];
    const float* W1_pt_l = (const float*)d_in[11];
    const float* W1_pt_r = (const float*)d_in[12];
    const float* W1_pu_l = (const float*)d_in[13];
    const float* W1_pu_r = (const float*)d_in[14];
    const float* W2_up_l = (const float*)d_in[15];
    const float* W2_up_r = (const float*)d_in[16];
    const float* W2_pt_l = (const float*)d_in[17];
    const float* W2_pt_r = (const float*)d_in[18];
    const float* W2_pu_l = (const float*)d_in[19];
    const float* W2_pu_r = (const float*)d_in[20];
    const float* b1_up = (const float*)d_in[21];
    const float* b1_pt = (const float*)d_in[22];
    const float* b1_pu = (const float*)d_in[23];
    const float* b2_up = (const float*)d_in[24];
    const float* b2_pt = (const float*)d_in[25];
    const float* b2_pu = (const float*)d_in[26];

    int n_user = in_sizes[0] / 64;
    int n_problem = in_sizes[1] / 64;
    int n_topic = in_sizes[2] / 64;
    int E_up = in_sizes[3];
    int E_pt = in_sizes[5];
    int E_pu = in_sizes[7];
    int E_tot = E_up + E_pt + E_pu;

    float* o_user = (float*)d_out;
    float* o_problem = o_user + (size_t)n_user * 64;
    float* o_topic = o_problem + (size_t)n_problem * 64;

    char* ws = (char*)d_ws;
    size_t off = 0;
    auto alloc = [&](size_t bytes) -> void* {
        void* p = ws + off;
        off += (bytes + 255) & ~(size_t)255;
        return p;
    };
    float* h_user    = (float*)alloc((size_t)n_user * 64 * 4);
    float* h_problem = (float*)alloc((size_t)n_problem * 64 * 4);
    float* h_topic   = (float*)alloc((size_t)n_topic * 64 * 4);
    // y buffers; the front of this region doubles as ebuf (int2 per edge) during CSR build
    float* y_up = (float*)alloc((size_t)n_user * 64 * 4);
    float* y_pt = (float*)alloc((size_t)n_problem * 64 * 4);
    float* y_pu = (float*)alloc((size_t)n_problem * 64 * 4);
    int2* ebuf = (int2*)y_up;  // 16.5MB needed, 23MB available before first transform

    auto cdiv = [](int a, int b) { return (a + b - 1) / b; };

    // buckets: relations ordered [up(dst=problem), pt(dst=topic), pu(dst=user)]
    int nb0 = cdiv(n_problem, 128), nb1 = cdiv(n_topic, 128), nb2 = cdiv(n_user, 128);
    int NB = nb0 + nb1 + nb2;

    int* gcnt  = (int*)alloc((size_t)(NB) * 4);
    int* bbase = (int*)alloc((size_t)(NB + 1) * 4);
    int* bcur  = (int*)alloc((size_t)(NB + 1) * 4);
    int* rowcat = (int*)alloc((size_t)(n_problem + n_topic + n_user + 3) * 4);
    int* ccsr  = (int*)alloc((size_t)E_tot * 4);

    BJobs B;
    B.src[0] = up_src; B.dst[0] = up_dst; B.E[0] = E_up;
    B.src[1] = pt_src; B.dst[1] = pt_dst; B.E[1] = E_pt;
    B.src[2] = pu_src; B.dst[2] = pu_dst; B.E[2] = E_pu;
    B.Eoff[0] = 0; B.Eoff[1] = E_up; B.Eoff[2] = E_up + E_pt; B.Eoff[3] = E_tot;
    B.nboff[0] = 0; B.nboff[1] = nb0; B.nboff[2] = nb0 + nb1; B.nboff[3] = NB;
    B.ndst[0] = n_problem; B.ndst[1] = n_topic; B.ndst[2] = n_user;
    B.Roff[0] = 0; B.Roff[1] = n_problem + 1; B.Roff[2] = n_problem + 1 + n_topic + 1;
    B.chunk_off[0] = 0;
    for (int r = 0; r < 3; ++r) B.chunk_off[r + 1] = B.chunk_off[r] + cdiv(B.E[r], CHUNK_E);

    const int* row_up = rowcat + B.Roff[0];
    const int* row_pt = rowcat + B.Roff[1];
    const int* row_pu = rowcat + B.Roff[2];
    const int* csr_up = ccsr + B.Eoff[0];
    const int* csr_pt = ccsr + B.Eoff[1];
    const int* csr_pu = ccsr + B.Eoff[2];

    zero_kernel<<<cdiv(NB, 256), 256, 0, stream>>>(gcnt, NB);
    bhist_kernel<<<B.chunk_off[3], BLK, 0, stream>>>(B, gcnt, NB);
    bscan_kernel<<<1, BLK, 0, stream>>>(gcnt, bbase, bcur, NB);
    bbin_kernel<<<B.chunk_off[3], BLK, 0, stream>>>(B, bcur, ebuf, NB);
    bplace_kernel<<<B.nboff[3], BLK, 0, stream>>>(B, bbase, ebuf, ccsr, rowcat);

    // ---- layer 1 ----
    {
        TJobs T;
        const float* xs[6] = {x_user, x_problem, x_problem, x_problem, x_topic, x_user};
        const float* Ws[6] = {W1_up_l, W1_pt_l, W1_pu_l, W1_up_r, W1_pt_r, W1_pu_r};
        const float* bs[6] = {nullptr, nullptr, nullptr, b1_up, b1_pt, b1_pu};
        float* ys[6] = {y_up, y_pt, y_pu, h_problem, h_topic, h_user};
        int ns[6] = {n_user, n_problem, n_problem, n_problem, n_topic, n_user};
        T.boff[0] = 0;
        for (int j = 0; j < 6; ++j) {
            T.x[j] = xs[j]; T.W[j] = Ws[j]; T.b[j] = bs[j]; T.y[j] = ys[j]; T.n[j] = ns[j];
            T.boff[j + 1] = T.boff[j] + cdiv(ns[j], 64);
        }
        transform_kernel<<<T.boff[6], BLK, 0, stream>>>(T);

        GJobs G;
        const float* gy[3] = {y_pu, y_up, y_pt};
        const int* gr[3] = {row_pu, row_up, row_pt};
        const int* gc[3] = {csr_pu, csr_up, csr_pt};
        float* go[3] = {h_user, h_problem, h_topic};
        int gn[3] = {n_user, n_problem, n_topic};
        G.boff[0] = 0;
        for (int j = 0; j < 3; ++j) {
            G.y[j] = gy[j]; G.row[j] = gr[j]; G.csr[j] = gc[j]; G.out[j] = go[j]; G.n[j] = gn[j];
            G.boff[j + 1] = G.boff[j] + cdiv(gn[j], 4);
        }
        G.relu = 1;
        gather_kernel<<<G.boff[3], BLK, 0, stream>>>(G);
    }

    // ---- layer 2 ----
    {
        TJobs T;
        const float* xs[6] = {h_user, h_problem, h_problem, h_problem, h_topic, h_user};
        const float* Ws[6] = {W2_up_l, W2_pt_l, W2_pu_l, W2_up_r, W2_pt_r, W2_pu_r};
        const float* bs[6] = {nullptr, nullptr, nullptr, b2_up, b2_pt, b2_pu};
        float* ys[6] = {y_up, y_pt, y_pu, o_problem, o_topic, o_user};
        int ns[6] = {n_user, n_problem, n_problem, n_problem, n_topic, n_user};
        T.boff[0] = 0;
        for (int j = 0; j < 6; ++j) {
            T.x[j] = xs[j]; T.W[j] = Ws[j]; T.b[j] = bs[j]; T.y[j] = ys[j]; T.n[j] = ns[j];
            T.boff[j + 1] = T.boff[j] + cdiv(ns[j], 64);
        }
        transform_kernel<<<T.boff[6], BLK, 0, stream>>>(T);

        GJobs G;
        const float* gy[3] = {y_pu, y_up, y_pt};
        const int* gr[3] = {row_pu, row_up, row_pt};
        const int* gc[3] = {csr_pu, csr_up, csr_pt};
        float* go[3] = {o_user, o_problem, o_topic};
        int gn[3] = {n_user, n_problem, n_topic};
        G.boff[0] = 0;
        for (int j = 0; j < 3; ++j) {
            G.y[j] = gy[j]; G.row[j] = gr[j]; G.csr[j] = gc[j]; G.out[j] = go[j]; G.n[j] = gn[j];
            G.boff[j + 1] = G.boff[j] + cdiv(gn[j], 4);
        }
        G.relu = 0;
        gather_kernel<<<G.boff[3], BLK, 0, stream>>>(G);
    }
}